// Round 1
// 1478.732 us; speedup vs baseline: 1.1679x; 1.1679x over previous
//
#include <hip/hip_runtime.h>
#include <hip/hip_bf16.h>
#include <math.h>

#define Bd 2
#define Td 2048
#define Hd 16
#define Sd 64
#define Ed 1024
#define Fd 4096

typedef __attribute__((ext_vector_type(8))) short short8;
typedef __attribute__((ext_vector_type(4))) float f32x4;
typedef __hip_bfloat16 bf16;

__device__ __forceinline__ unsigned short f2bfu(float f){
  bf16 h = __float2bfloat16(f);
  unsigned short u;
  __builtin_memcpy(&u, &h, 2);
  return u;
}

// LDS-only barrier: does NOT drain vmcnt, so register prefetches (prev/K tiles)
// stay in flight across it. Memory-clobber asm on both sides pins ordering.
__device__ __forceinline__ void bar_lds(){
  asm volatile("s_waitcnt lgkmcnt(0)" ::: "memory");
  __builtin_amdgcn_s_barrier();
  asm volatile("" ::: "memory");
}

// ---------------- f32 -> bf16 conversion (grid-stride over float4) ----------------
__global__ __launch_bounds__(256) void cvt_bf16_kernel(const float* __restrict__ src,
                                                       bf16* __restrict__ dst, int n4){
  int i = blockIdx.x*256 + threadIdx.x;
  int stride = gridDim.x*256;
  for (; i < n4; i += stride){
    float4 v = ((const float4*)src)[i];
    bf16* d = dst + (size_t)i*4;
    d[0] = __float2bfloat16(v.x);
    d[1] = __float2bfloat16(v.y);
    d[2] = __float2bfloat16(v.z);
    d[3] = __float2bfloat16(v.w);
  }
}

// ---------------- kqv projection: x[b,t,:] x kqv_w[o,s] -> k,q,v bf16 [B,T,H,S] ----------------
__global__ __launch_bounds__(192) void kqv_kernel(const float* __restrict__ x, const float* __restrict__ w,
    bf16* __restrict__ kb, bf16* __restrict__ qb, bf16* __restrict__ vb){
  __shared__ float xs[Ed];
  int bt = blockIdx.x;
  int o = threadIdx.x;            // 0..191 : output channel of kqv_w
  const float* xrow = x + (size_t)bt*Ed;
  for (int i = o; i < Ed; i += 192) xs[i] = xrow[i];
  __syncthreads();
  float4 wr[16];
  const float4* w4 = (const float4*)(w + o*Sd);
  #pragma unroll
  for (int i = 0; i < 16; i++) wr[i] = w4[i];
  int part = o >> 6, sidx = o & 63;          // split order: k, q, v
  bf16* ob = (part == 0) ? kb : (part == 1 ? qb : vb);
  ob += (size_t)bt*Hd*Sd + sidx;
  for (int h = 0; h < Hd; h++){
    const float4* xh4 = (const float4*)(xs + h*Sd);
    float a0=0.f,a1=0.f,a2=0.f,a3=0.f;
    #pragma unroll
    for (int i = 0; i < 16; i++){
      float4 xv = xh4[i];   // LDS broadcast (all lanes same addr)
      a0 = fmaf(xv.x, wr[i].x, a0);
      a1 = fmaf(xv.y, wr[i].y, a1);
      a2 = fmaf(xv.z, wr[i].z, a2);
      a3 = fmaf(xv.w, wr[i].w, a3);
    }
    ob[h*Sd] = __float2bfloat16((a0+a1)+(a2+a3));
  }
}

// ---------------- transpose v [B,T,H,S] -> vt [B,H,S,T] ----------------
__global__ __launch_bounds__(256) void vt_kernel(const bf16* __restrict__ vb, bf16* __restrict__ vt){
  __shared__ bf16 tile[64][72];
  int t0 = blockIdx.x*64, h = blockIdx.y, b = blockIdx.z;
  int tid = threadIdx.x;
  for (int i = tid; i < 4096; i += 256){
    int tt = i >> 6, s = i & 63;
    tile[tt][s] = vb[(((size_t)b*Td + t0 + tt)*Hd + h)*Sd + s];
  }
  __syncthreads();
  for (int i = tid; i < 4096; i += 256){
    int s = i >> 6, tt = i & 63;
    vt[(((size_t)b*Hd + h)*Sd + s)*Td + t0 + tt] = tile[tt][s];
  }
}

// ---------------- Fused attention (flash-style, single pass) ----------------
// scores = qk^T/8 + prev -> att (output), online softmax (m,l) with O-rescale,
// O = P V -> resb bf16 [B*T, E].
// block = 1024 thr = 16 waves, wave w <-> head w. grid = (T/16, B).
// Per 32-j tile, two barrier intervals:
//   X: PV(jt-1) MFMAs || QK(jt) MFMAs || K(jt+1) prefetch   (reads Ps/Msc, writes Ss)
//   Y: scores+prev, att stores, stats, P->Ps, sc->Msc, prev(jt+1) prefetch
__global__ __launch_bounds__(1024) void attn_fused_kernel(
    const bf16* __restrict__ qb, const bf16* __restrict__ kb,
    const bf16* __restrict__ vtp, const float* __restrict__ prev,
    float* __restrict__ att, bf16* __restrict__ resb){
  constexpr int NT = Td/32;
  int i0 = blockIdx.x*16, b = blockIdx.y;
  int tid = threadIdx.x;
  int wid = tid >> 6, lane = tid & 63, col = lane & 15, quad = lane >> 4;
  __shared__ float Ss[16][17][33];               // [head][row i][col j 0..31]; h-stride 561w == 17 mod 32 -> 2-way reads
  __shared__ __align__(16) bf16 Ps[16][17][40];  // [head][i][j] P in bf16 (A-frag source)
  __shared__ float Msc[16][16];                  // per-tile O rescale factor [i][h]
  __shared__ float Linv[16][16];                 // 1/l [i][h]

  // A-frag q: A[m=col][k=quad*8+e]
  const bf16* qbase = qb + (((size_t)b*Td + i0 + col)*Hd + wid)*Sd + quad*8;
  short8 aq0 = *(const short8*)(qbase);
  short8 aq1 = *(const short8*)(qbase + 32);

  int ii = wid, co = (tid >> 4) & 3, h2 = tid & 15;   // interval-Y decode: (row ii, j-chunk co, head h2)
  float m_t = -1e30f, l_t = 0.f;

  // V B-frag base: vt[b][h=wid][s=col(+st*16)][t=j]
  const bf16* vbase = vtp + (((size_t)b*Hd + wid)*Sd + col)*Td;
  // K base: kb[b][j+col][wid][quad*8+e]
  const bf16* kb0 = kb + (((size_t)b*Td + col)*Hd + wid)*Sd + quad*8;
  const size_t KJ = (size_t)Hd*Sd;               // element stride per j row in kb

  // prefetch K tile 0 (j = col and j = 16+col)
  short8 kc0 = *(const short8*)(kb0);
  short8 kc1 = *(const short8*)(kb0 + 32);
  short8 kc2 = *(const short8*)(kb0 + 16*KJ);
  short8 kc3 = *(const short8*)(kb0 + 16*KJ + 32);

  // prefetch prev tile 0 into registers
  const size_t pbase = (((size_t)b*Td + i0 + ii)*Td)*(size_t)Hd + h2;
  float pf[8];
  #pragma unroll
  for (int e = 0; e < 8; e++) pf[e] = prev[pbase + (size_t)(co*8 + e)*Hd];

  f32x4 O0 = {0.f,0.f,0.f,0.f}, O1 = O0, O2 = O0, O3 = O0;

#define PV_TILE(JP) do { \
    float s0 = Msc[quad*4+0][wid]; \
    float s1 = Msc[quad*4+1][wid]; \
    float s2 = Msc[quad*4+2][wid]; \
    float s3 = Msc[quad*4+3][wid]; \
    O0[0]*=s0; O0[1]*=s1; O0[2]*=s2; O0[3]*=s3; \
    O1[0]*=s0; O1[1]*=s1; O1[2]*=s2; O1[3]*=s3; \
    O2[0]*=s0; O2[1]*=s1; O2[2]*=s2; O2[3]*=s3; \
    O3[0]*=s0; O3[1]*=s1; O3[2]*=s2; O3[3]*=s3; \
    short8 ap  = *(const short8*)(&Ps[wid][col][quad*8]); \
    short8 bv0 = *(const short8*)(vbase + (JP) + quad*8); \
    short8 bv1 = *(const short8*)(vbase + (size_t)16*Td + (JP) + quad*8); \
    short8 bv2 = *(const short8*)(vbase + (size_t)32*Td + (JP) + quad*8); \
    short8 bv3 = *(const short8*)(vbase + (size_t)48*Td + (JP) + quad*8); \
    O0 = __builtin_amdgcn_mfma_f32_16x16x32_bf16(ap, bv0, O0, 0, 0, 0); \
    O1 = __builtin_amdgcn_mfma_f32_16x16x32_bf16(ap, bv1, O1, 0, 0, 0); \
    O2 = __builtin_amdgcn_mfma_f32_16x16x32_bf16(ap, bv2, O2, 0, 0, 0); \
    O3 = __builtin_amdgcn_mfma_f32_16x16x32_bf16(ap, bv3, O3, 0, 0, 0); \
  } while (0)

  for (int jt = 0; jt < NT; jt++){
    int j0 = jt*32;
    // ---------- interval X ----------
    if (jt > 0){
      PV_TILE(j0 - 32);
    }
    f32x4 acc0 = {0.f,0.f,0.f,0.f}, acc1 = acc0;
    acc0 = __builtin_amdgcn_mfma_f32_16x16x32_bf16(aq0, kc0, acc0, 0, 0, 0);
    acc0 = __builtin_amdgcn_mfma_f32_16x16x32_bf16(aq1, kc1, acc0, 0, 0, 0);
    acc1 = __builtin_amdgcn_mfma_f32_16x16x32_bf16(aq0, kc2, acc1, 0, 0, 0);
    acc1 = __builtin_amdgcn_mfma_f32_16x16x32_bf16(aq1, kc3, acc1, 0, 0, 0);
    {
      // K prefetch for next tile (wraps harmlessly on last iter)
      int jn = (jt+1 < NT) ? (j0+32) : 0;
      const bf16* knb = kb0 + (size_t)jn*KJ;
      kc0 = *(const short8*)(knb);
      kc1 = *(const short8*)(knb + 32);
      kc2 = *(const short8*)(knb + 16*KJ);
      kc3 = *(const short8*)(knb + 16*KJ + 32);
    }
    #pragma unroll
    for (int r = 0; r < 4; r++){
      Ss[wid][quad*4+r][col]      = acc0[r];   // D: row=quad*4+r, col=lane&15
      Ss[wid][quad*4+r][16 + col] = acc1[r];
    }
    bar_lds();
    // ---------- interval Y ----------
    float v[8];
    #pragma unroll
    for (int e = 0; e < 8; e++) v[e] = Ss[h2][ii][co*8+e]*0.125f + pf[e];
    {
      // prev prefetch for next tile (redundant reload of last tile on final iter)
      int jn = (jt+1 < NT) ? (j0+32) : j0;
      #pragma unroll
      for (int e = 0; e < 8; e++) pf[e] = prev[pbase + (size_t)(jn + co*8 + e)*Hd];
    }
    size_t gb = pbase + (size_t)(j0 + co*8)*Hd;
    #pragma unroll
    for (int e = 0; e < 8; e++) att[gb + (size_t)e*Hd] = v[e];
    // online stats per (row ii, head h2); 4 co-partners are lane bits 4..5
    float mx = fmaxf(fmaxf(fmaxf(v[0],v[1]), fmaxf(v[2],v[3])),
                     fmaxf(fmaxf(v[4],v[5]), fmaxf(v[6],v[7])));
    mx = fmaxf(mx, __shfl_xor(mx, 16));
    mx = fmaxf(mx, __shfl_xor(mx, 32));
    float m_new = fmaxf(m_t, mx);
    float sc = __expf(m_t - m_new);
    float p[8]; float ps = 0.f;
    #pragma unroll
    for (int e = 0; e < 8; e++){ p[e] = __expf(v[e] - m_new); ps += p[e]; }
    l_t = l_t*sc + ps;
    m_t = m_new;
    if (co == 0) Msc[ii][h2] = sc;
    short8 sv;
    #pragma unroll
    for (int e = 0; e < 8; e++) sv[e] = (short)f2bfu(p[e]);
    *(short8*)(&Ps[h2][ii][co*8]) = sv;
    bar_lds();
  }
  // final PV for last tile
  PV_TILE(Td - 32);
#undef PV_TILE

  // combine l over the 4 co-partners; write 1/l
  float lsum = l_t + __shfl_xor(l_t, 16);
  lsum += __shfl_xor(lsum, 32);
  if (co == 0) Linv[ii][h2] = 1.0f / lsum;
  bar_lds();
  float li0 = Linv[quad*4+0][wid];
  float li1 = Linv[quad*4+1][wid];
  float li2 = Linv[quad*4+2][wid];
  float li3 = Linv[quad*4+3][wid];
  #pragma unroll
  for (int r = 0; r < 4; r++){
    float li = (r==0) ? li0 : (r==1) ? li1 : (r==2) ? li2 : li3;
    size_t base = ((size_t)b*Td + i0 + quad*4 + r)*Ed + wid*Sd + col;
    resb[base +  0] = __float2bfloat16(O0[r]*li);
    resb[base + 16] = __float2bfloat16(O1[r]*li);
    resb[base + 32] = __float2bfloat16(O2[r]*li);
    resb[base + 48] = __float2bfloat16(O3[r]*li);
  }
}

// ---------------- bf16 GEMM  C[M,N] = A[M,K] * Bw[N,K]^T  + fused epilogue ----------------
// EPI 0: outf = C + addend            (proj: + x residual)
// EPI 1: outb = gelu_exact(C + bias)  (ff1 -> bf16 hidden)
// EPI 2: outf = C + bias + addend     (ff2: + b2 + x1 residual)
template<int EPI>
__global__ __launch_bounds__(256) void gemm_kernel(
    const bf16* __restrict__ A, const bf16* __restrict__ Bw,
    int M, int N, int K,
    const float* __restrict__ bias, const float* __restrict__ addend,
    float* __restrict__ outf, bf16* __restrict__ outb){
  __shared__ __align__(16) bf16 As[128*32];
  __shared__ __align__(16) bf16 Bs[128*32];
  int tid = threadIdx.x;
  int wid = tid >> 6, lane = tid & 63, col = lane & 15, quad = lane >> 4;
  int n0 = blockIdx.x*128, m0 = blockIdx.y*128;
  int wy = wid >> 1, wx = wid & 1;
  f32x4 acc[4][4];
  #pragma unroll
  for (int i = 0; i < 4; i++)
    #pragma unroll
    for (int j = 0; j < 4; j++) acc[i][j] = (f32x4){0.f,0.f,0.f,0.f};

  int srow = tid >> 2, skc = tid & 3;
  for (int k0 = 0; k0 < K; k0 += 32){
    __syncthreads();
    #pragma unroll
    for (int i = 0; i < 2; i++){
      const bf16* gpa = A + (size_t)(m0 + srow + i*64)*K + k0 + skc*8;
      bf16* lpa = As + ((size_t)i*256 + wid*64)*8;   // wave-uniform base + lane*16B
      __builtin_amdgcn_global_load_lds((const __attribute__((address_space(1))) unsigned int*)gpa,
                                       (__attribute__((address_space(3))) unsigned int*)lpa, 16, 0, 0);
      const bf16* gpb = Bw + (size_t)(n0 + srow + i*64)*K + k0 + skc*8;
      bf16* lpb = Bs + ((size_t)i*256 + wid*64)*8;
      __builtin_amdgcn_global_load_lds((const __attribute__((address_space(1))) unsigned int*)gpb,
                                       (__attribute__((address_space(3))) unsigned int*)lpb, 16, 0, 0);
    }
    __syncthreads();
    short8 af[4], bf_[4];
    #pragma unroll
    for (int t = 0; t < 4; t++){
      af[t]  = *(const short8*)(As + (wy*64 + t*16 + col)*32 + quad*8);
      bf_[t] = *(const short8*)(Bs + (wx*64 + t*16 + col)*32 + quad*8);
    }
    #pragma unroll
    for (int i = 0; i < 4; i++)
      #pragma unroll
      for (int j = 0; j < 4; j++)
        acc[i][j] = __builtin_amdgcn_mfma_f32_16x16x32_bf16(af[i], bf_[j], acc[i][j], 0, 0, 0);
  }
  #pragma unroll
  for (int i = 0; i < 4; i++){
    #pragma unroll
    for (int r = 0; r < 4; r++){
      int mrow = m0 + wy*64 + i*16 + quad*4 + r;
      #pragma unroll
      for (int j = 0; j < 4; j++){
        int ncol = n0 + wx*64 + j*16 + col;
        float v = acc[i][j][r];
        size_t oidx = (size_t)mrow*N + ncol;
        if (EPI == 0){
          outf[oidx] = v + addend[oidx];
        } else if (EPI == 1){
          float t = v + bias[ncol];
          outb[oidx] = __float2bfloat16(0.5f*t*(1.0f + erff(t*0.70710678118f)));
        } else {
          outf[oidx] = v + bias[ncol] + addend[oidx];
        }
      }
    }
  }
}

// ---------------- row LayerNorm over E=1024 ----------------
__global__ __launch_bounds__(256) void ln_kernel(const float* __restrict__ in,
    const float* __restrict__ gw, const float* __restrict__ gb,
    float* __restrict__ outf, bf16* __restrict__ outb){
  int row = blockIdx.x, tid = threadIdx.x;
  const float4* r4 = (const float4*)(in + (size_t)row*Ed);
  float4 xv = r4[tid];
  float s  = xv.x + xv.y + xv.z + xv.w;
  float ss = xv.x*xv.x + xv.y*xv.y + xv.z*xv.z + xv.w*xv.w;
  #pragma unroll
  for (int off = 32; off > 0; off >>= 1){
    s  += __shfl_down(s, off);
    ss += __shfl_down(ss, off);
  }
  __shared__ float sb[4], ssb[4], mv[2];
  int lane = tid & 63, wv = tid >> 6;
  if (lane == 0){ sb[wv] = s; ssb[wv] = ss; }
  __syncthreads();
  if (tid == 0){
    float S  = sb[0]+sb[1]+sb[2]+sb[3];
    float SS = ssb[0]+ssb[1]+ssb[2]+ssb[3];
    float mean = S*(1.0f/Ed);
    float var  = SS*(1.0f/Ed) - mean*mean;
    mv[0] = mean; mv[1] = rsqrtf(var + 1e-5f);
  }
  __syncthreads();
  float mean = mv[0], rstd = mv[1];
  float4 wv4 = ((const float4*)gw)[tid];
  float4 bv4 = ((const float4*)gb)[tid];
  float4 o;
  o.x = (xv.x - mean)*rstd*wv4.x + bv4.x;
  o.y = (xv.y - mean)*rstd*wv4.y + bv4.y;
  o.z = (xv.z - mean)*rstd*wv4.z + bv4.z;
  o.w = (xv.w - mean)*rstd*wv4.w + bv4.w;
  if (outf) ((float4*)(outf + (size_t)row*Ed))[tid] = o;
  if (outb){
    bf16* ob = outb + (size_t)row*Ed + tid*4;
    ob[0] = __float2bfloat16(o.x);
    ob[1] = __float2bfloat16(o.y);
    ob[2] = __float2bfloat16(o.z);
    ob[3] = __float2bfloat16(o.w);
  }
}

extern "C" void kernel_launch(void* const* d_in, const int* in_sizes, int n_in,
                              void* d_out, int out_size, void* d_ws, size_t ws_size,
                              hipStream_t stream){
  (void)in_sizes; (void)n_in; (void)out_size; (void)ws_size;
  const float* x      = (const float*)d_in[0];
  const float* prev   = (const float*)d_in[1];
  const float* kqv_w  = (const float*)d_in[2];
  const float* proj_w = (const float*)d_in[3];
  const float* ln1_w  = (const float*)d_in[4];
  const float* ln1_b  = (const float*)d_in[5];
  const float* ln2_w  = (const float*)d_in[6];
  const float* ln2_b  = (const float*)d_in[7];
  const float* ff_w1  = (const float*)d_in[8];
  const float* ff_b1  = (const float*)d_in[9];
  const float* ff_w2  = (const float*)d_in[10];
  const float* ff_b2  = (const float*)d_in[11];

  float* out_x2  = (float*)d_out;
  float* out_att = out_x2 + (size_t)Bd*Td*Ed;

  char* wsp = (char*)d_ws;
  auto alloc = [&](size_t bytes)->char*{
    char* p = wsp;
    wsp += (bytes + 255) & ~(size_t)255;
    return p;
  };
  const size_t NTOK = (size_t)Bd*Td;            // 4096
  bf16* kb    = (bf16*)alloc(NTOK*Ed*2);        // k  [B,T,H,S]
  bf16* qb    = (bf16*)alloc(NTOK*Ed*2);        // q
  bf16* vb    = (bf16*)alloc(NTOK*Ed*2);        // v
  bf16* vtb   = (bf16*)alloc(NTOK*Ed*2);        // v^T [B,H,S,T]
  bf16* resb  = (bf16*)alloc(NTOK*Ed*2);        // attention out [B*T,E]
  bf16* x1b   = (bf16*)alloc(NTOK*Ed*2);        // x1 bf16
  bf16* hidb  = (bf16*)alloc(NTOK*Fd*2);        // gelu hidden [B*T,4E]
  bf16* pwb   = (bf16*)alloc((size_t)Ed*Ed*2);  // proj_w bf16
  bf16* w1b   = (bf16*)alloc((size_t)Fd*Ed*2);  // ff_w1 bf16
  bf16* w2b   = (bf16*)alloc((size_t)Ed*Fd*2);  // ff_w2 bf16
  float* sum_ws  = (float*)alloc(NTOK*Ed*4);    // pre-LN sums (reused for both LNs)
  float* x1f     = (float*)alloc(NTOK*Ed*4);    // x1 fp32 (residual for ff2)

  // weight conversions
  cvt_bf16_kernel<<<1024, 256, 0, stream>>>(proj_w, pwb, (Ed*Ed)/4);
  cvt_bf16_kernel<<<4096, 256, 0, stream>>>(ff_w1, w1b, (Fd*Ed)/4);
  cvt_bf16_kernel<<<4096, 256, 0, stream>>>(ff_w2, w2b, (Ed*Fd)/4);

  // kqv + v transpose
  kqv_kernel<<<Bd*Td, 192, 0, stream>>>(x, kqv_w, kb, qb, vb);
  vt_kernel<<<dim3(Td/64, Hd, Bd), 256, 0, stream>>>(vb, vtb);

  // fused attention: att_score output + softmax + PV in one pass
  attn_fused_kernel<<<dim3(Td/16, Bd), 1024, 0, stream>>>(qb, kb, vtb, prev, out_att, resb);

  // proj + x residual
  gemm_kernel<0><<<dim3(Ed/128, (Bd*Td)/128), 256, 0, stream>>>(
      resb, pwb, Bd*Td, Ed, Ed, nullptr, x, sum_ws, nullptr);
  // LN1 -> x1 (f32 + bf16)
  ln_kernel<<<Bd*Td, 256, 0, stream>>>(sum_ws, ln1_w, ln1_b, x1f, x1b);
  // ff1 + gelu -> hidden bf16
  gemm_kernel<1><<<dim3(Fd/128, (Bd*Td)/128), 256, 0, stream>>>(
      x1b, w1b, Bd*Td, Fd, Ed, ff_b1, nullptr, nullptr, hidb);
  // ff2 + b2 + x1 residual
  gemm_kernel<2><<<dim3(Ed/128, (Bd*Td)/128), 256, 0, stream>>>(
      hidb, w2b, Bd*Td, Ed, Fd, ff_b2, x1f, sum_ws, nullptr);
  // LN2 -> x2
  ln_kernel<<<Bd*Td, 256, 0, stream>>>(sum_ws, ln2_w, ln2_b, out_x2, nullptr);
}